// Round 7
// baseline (484.488 us; speedup 1.0000x reference)
//
#include <hip/hip_runtime.h>
#include <hip/hip_bf16.h>

#define N    8192
#define INF  256
#define OUTF 128
#define ALPHA 0.2f
#define MIN2(x, y) ((x) < (y) ? (x) : (y))

typedef __attribute__((ext_vector_type(8))) short bf16x8;
typedef __attribute__((ext_vector_type(4))) float f32x4;

__device__ __forceinline__ unsigned short f2bf(float x) {
    union { float f; unsigned u; } v; v.f = x;
    unsigned r = v.u + 0x7fff + ((v.u >> 16) & 1);   // RNE
    return (unsigned short)(r >> 16);
}

// ---------------- Kernel 1: WhT_b = blocked bf16 (h@W)^T ; f1 ; f2 ----------
// 8 rows/block, 256 threads, grid 1024. hs row-major in LDS (coalesced stage,
// broadcast reads). W direct from L2, unroll-8. WhT_b layout:
// [jblk=j/32][c][j%32] ushort (8 KB/tile) -> k2 B-loads are lane-contiguous.
__global__ __launch_bounds__(256) void k1_wh(
        const float* __restrict__ h, const float* __restrict__ W,
        const float* __restrict__ a,
        unsigned short* __restrict__ WhTb, float* __restrict__ f1, float* __restrict__ f2) {
    __shared__ float hs[8][INF];          // 8 KB
    const int t  = threadIdx.x;
    const int i0 = blockIdx.x * 8;

    #pragma unroll
    for (int u = 0; u < 2; ++u) {
        int idx = u * 256 + t;
        int r   = idx >> 6;               // 0..7 (wave-uniform)
        int kq  = idx & 63;               // lane-consecutive -> coalesced
        *(float4*)&hs[r][kq * 4] = *(const float4*)(h + (size_t)(i0 + r) * INF + kq * 4);
    }
    __syncthreads();

    const int rg = t >> 5;                // 0..7 : row
    const int ct = t & 31;                // 0..31 : col group
    float acc[4] = {0.f, 0.f, 0.f, 0.f};

    #pragma unroll 8
    for (int k = 0; k < INF; ++k) {
        float4 wv = *(const float4*)(W + (size_t)k * OUTF + ct * 4);
        float  hx = hs[rg][k];
        acc[0] += hx * wv.x; acc[1] += hx * wv.y;
        acc[2] += hx * wv.z; acc[3] += hx * wv.w;
    }

    const int r0 = i0 + rg;               // j index
    const int jb = r0 >> 5;
    const int jo = r0 & 31;
    #pragma unroll
    for (int cc = 0; cc < 4; ++cc)
        WhTb[(size_t)jb * 4096 + (ct * 4 + cc) * 32 + jo] = f2bf(acc[cc]);

    const float4 a1v = *(const float4*)(a + ct * 4);
    const float4 a2v = *(const float4*)(a + OUTF + ct * 4);
    float p1 = acc[0]*a1v.x + acc[1]*a1v.y + acc[2]*a1v.z + acc[3]*a1v.w;
    float p2 = acc[0]*a2v.x + acc[1]*a2v.y + acc[2]*a2v.z + acc[3]*a2v.w;
    #pragma unroll
    for (int off = 16; off > 0; off >>= 1) {
        p1 += __shfl_down(p1, off, 32);
        p2 += __shfl_down(p2, off, 32);
    }
    if (ct == 0) { f1[r0] = p1; f2[r0] = p2; }
}

// ---------------- Kernel 2: MFMA attention, deep-pipelined --------------------
// One-pass masked softmax (exact vs ref; verified rounds 1-6). 16 rows/block,
// 256 threads, grid 512 (2 blocks/CU at (256,2) -> 256-VGPR budget, no spill).
// Wave w owns j in [w*2048,(w+1)*2048), NT=64 K-steps, unrolled x4 with named
// rotating prefetch buffers: adj depth-4 (HBM ~900cyc), f2 depth-2, B-frag
// depth-1 (L2 ~200cyc). Epilogue combines 4 waves via LDS, writes out.
struct PFA { int4 a0, a1; };
struct FG  { float4 g0, g1; };
struct BFr { bf16x8 b0, b1, b2, b3, b4, b5, b6, b7; };

__device__ __forceinline__ PFA ldadj(const int* __restrict__ ap, int jt) {
    PFA p;
    p.a0 = *(const int4*)(ap + (size_t)jt * 32);
    p.a1 = *(const int4*)(ap + (size_t)jt * 32 + 4);
    return p;
}
__device__ __forceinline__ FG ldf2(const float* __restrict__ gp, int jt) {
    FG g;
    g.g0 = *(const float4*)(gp + (size_t)jt * 32);
    g.g1 = *(const float4*)(gp + (size_t)jt * 32 + 4);
    return g;
}
__device__ __forceinline__ BFr ldb(const unsigned short* __restrict__ base) {
    BFr r;
    r.b0 = *(const bf16x8*)(base);
    r.b1 = *(const bf16x8*)(base + 512);
    r.b2 = *(const bf16x8*)(base + 1024);
    r.b3 = *(const bf16x8*)(base + 1536);
    r.b4 = *(const bf16x8*)(base + 2048);
    r.b5 = *(const bf16x8*)(base + 2560);
    r.b6 = *(const bf16x8*)(base + 3072);
    r.b7 = *(const bf16x8*)(base + 3584);
    return r;
}

__device__ __forceinline__ float pleak(float f1r, float fv, int av, float& dsum) {
    float s = f1r + fv;
    float e = fmaxf(s, ALPHA * s);        // leaky-relu, branch-free
    float p = (av > 0) ? __expf(e) : 0.f;
    dsum += p;                            // fp32 den (≤1e-5 rel delta vs ref)
    return p;
}

// step: consume AB (adj, tile JT), GB (f2, tile JT), WB (B-frags, tile JT);
// prefetch WNEXT<-JT+1, GB<-JT+2, AB<-JT+4.
#define K2S(AB, GB, WB, WNEXT, JT)                                          \
    {                                                                       \
        int4   A0_ = AB.a0, A1_ = AB.a1;                                    \
        float4 F0_ = GB.g0, F1_ = GB.g1;                                    \
        WNEXT = ldb(wb + (size_t)MIN2((JT) + 1, NT - 1) * 4096);            \
        GB    = ldf2(f2p, MIN2((JT) + 2, NT - 1));                          \
        AB    = ldadj(adjp, MIN2((JT) + 4, NT - 1));                        \
        float p0_ = pleak(f1r, F0_.x, A0_.x, dsum);                         \
        float p1_ = pleak(f1r, F0_.y, A0_.y, dsum);                         \
        float p2_ = pleak(f1r, F0_.z, A0_.z, dsum);                         \
        float p3_ = pleak(f1r, F0_.w, A0_.w, dsum);                         \
        float p4_ = pleak(f1r, F1_.x, A1_.x, dsum);                         \
        float p5_ = pleak(f1r, F1_.y, A1_.y, dsum);                         \
        float p6_ = pleak(f1r, F1_.z, A1_.z, dsum);                         \
        float p7_ = pleak(f1r, F1_.w, A1_.w, dsum);                         \
        union { __hip_bfloat162 h[4]; bf16x8 v; } pk_;                      \
        pk_.h[0] = __float22bfloat162_rn(make_float2(p0_, p1_));            \
        pk_.h[1] = __float22bfloat162_rn(make_float2(p2_, p3_));            \
        pk_.h[2] = __float22bfloat162_rn(make_float2(p4_, p5_));            \
        pk_.h[3] = __float22bfloat162_rn(make_float2(p6_, p7_));            \
        bf16x8 afrag = pk_.v;                                               \
        acc0 = __builtin_amdgcn_mfma_f32_16x16x32_bf16(afrag, WB.b0, acc0, 0, 0, 0); \
        acc1 = __builtin_amdgcn_mfma_f32_16x16x32_bf16(afrag, WB.b1, acc1, 0, 0, 0); \
        acc2 = __builtin_amdgcn_mfma_f32_16x16x32_bf16(afrag, WB.b2, acc2, 0, 0, 0); \
        acc3 = __builtin_amdgcn_mfma_f32_16x16x32_bf16(afrag, WB.b3, acc3, 0, 0, 0); \
        acc4 = __builtin_amdgcn_mfma_f32_16x16x32_bf16(afrag, WB.b4, acc4, 0, 0, 0); \
        acc5 = __builtin_amdgcn_mfma_f32_16x16x32_bf16(afrag, WB.b5, acc5, 0, 0, 0); \
        acc6 = __builtin_amdgcn_mfma_f32_16x16x32_bf16(afrag, WB.b6, acc6, 0, 0, 0); \
        acc7 = __builtin_amdgcn_mfma_f32_16x16x32_bf16(afrag, WB.b7, acc7, 0, 0, 0); \
    }

__global__ __launch_bounds__(256, 2) void k2_attn(
        const int* __restrict__ adj, const unsigned short* __restrict__ WhTb,
        const float* __restrict__ f1, const float* __restrict__ f2,
        float* __restrict__ out) {
    __shared__ float red[4][16][132];     // 33.8 KB (pitch 132: 2-way max = free)
    __shared__ float den_s[4][16];

    const int t    = threadIdx.x;
    const int w    = t >> 6;              // 0..3 : wave = j-range
    const int ln   = t & 63;
    const int m16  = ln & 15;             // A row within 16-tile
    const int quad = ln >> 4;             // 0..3
    const int i0   = blockIdx.x * 16;
    const int row  = i0 + m16;

    const float f1r = f1[row];
    const int   j0w = w * (N / 4);
    const int   NT  = (N / 4) / 32;       // 64 K-steps

    const int*            adjp = adj + (size_t)row * N + j0w + quad * 8;
    const float*          f2p  = f2 + j0w + quad * 8;
    const unsigned short* wb   = WhTb + (size_t)w * 64 * 4096 + (m16 * 32 + quad * 8);

    f32x4 acc0 = {0.f,0.f,0.f,0.f}, acc1 = {0.f,0.f,0.f,0.f};
    f32x4 acc2 = {0.f,0.f,0.f,0.f}, acc3 = {0.f,0.f,0.f,0.f};
    f32x4 acc4 = {0.f,0.f,0.f,0.f}, acc5 = {0.f,0.f,0.f,0.f};
    f32x4 acc6 = {0.f,0.f,0.f,0.f}, acc7 = {0.f,0.f,0.f,0.f};
    float dsum = 0.f;

    // prologue: adj depth-4, f2 depth-2, B depth-1 (all named buffers)
    PFA pa0 = ldadj(adjp, 0), pa1 = ldadj(adjp, 1);
    PFA pa2 = ldadj(adjp, 2), pa3 = ldadj(adjp, 3);
    FG  pg0 = ldf2(f2p, 0),  pg1 = ldf2(f2p, 1);
    BFr pw0 = ldb(wb), pw1;

    for (int jt = 0; jt < NT; jt += 4) {
        K2S(pa0, pg0, pw0, pw1, jt)
        K2S(pa1, pg1, pw1, pw0, jt + 1)
        K2S(pa2, pg0, pw0, pw1, jt + 2)
        K2S(pa3, pg1, pw1, pw0, jt + 3)
    }

    // den: sum the 4 quads of each row within the wave
    dsum += __shfl_xor(dsum, 16);
    dsum += __shfl_xor(dsum, 32);
    if (quad == 0) den_s[w][m16] = dsum;

    // stage acc partials: D layout col=lane&15, row=quad*4+reg
    #pragma unroll
    for (int r = 0; r < 4; ++r) {
        red[w][quad * 4 + r][0 * 16 + m16] = acc0[r];
        red[w][quad * 4 + r][1 * 16 + m16] = acc1[r];
        red[w][quad * 4 + r][2 * 16 + m16] = acc2[r];
        red[w][quad * 4 + r][3 * 16 + m16] = acc3[r];
        red[w][quad * 4 + r][4 * 16 + m16] = acc4[r];
        red[w][quad * 4 + r][5 * 16 + m16] = acc5[r];
        red[w][quad * 4 + r][6 * 16 + m16] = acc6[r];
        red[w][quad * 4 + r][7 * 16 + m16] = acc7[r];
    }
    __syncthreads();

    // combine 4 waves, normalize, write out (256 threads x 2 float4 = 16x128)
    #pragma unroll
    for (int e = 0; e < 2; ++e) {
        int idx = e * 256 + t;
        int r   = idx >> 5;               // 0..15
        int c4  = (idx & 31) * 4;
        float4 s0 = *(const float4*)&red[0][r][c4];
        float4 s1 = *(const float4*)&red[1][r][c4];
        float4 s2 = *(const float4*)&red[2][r][c4];
        float4 s3 = *(const float4*)&red[3][r][c4];
        float dtot = den_s[0][r] + den_s[1][r] + den_s[2][r] + den_s[3][r];
        float inv  = 1.0f / dtot;
        float4 o;
        o.x = (s0.x + s1.x + s2.x + s3.x) * inv;
        o.y = (s0.y + s1.y + s2.y + s3.y) * inv;
        o.z = (s0.z + s1.z + s2.z + s3.z) * inv;
        o.w = (s0.w + s1.w + s2.w + s3.w) * inv;
        *(float4*)(out + (size_t)(i0 + r) * OUTF + c4) = o;
    }
}

extern "C" void kernel_launch(void* const* d_in, const int* in_sizes, int n_in,
                              void* d_out, int out_size, void* d_ws, size_t ws_size,
                              hipStream_t stream) {
    const float* h   = (const float*)d_in[0];   // (8192, 256)
    const int*   adj = (const int*)  d_in[1];   // (8192, 8192)
    const float* W   = (const float*)d_in[2];   // (256, 128)
    const float* a   = (const float*)d_in[3];   // (256, 1)
    float* out = (float*)d_out;                 // (8192, 128)

    unsigned short* WhTb = (unsigned short*)d_ws;   // 2 MB blocked bf16
    float* f1 = (float*)(WhTb + (size_t)N * OUTF);
    float* f2 = f1 + N;

    k1_wh  <<<N / 8, 256, 0, stream>>>(h, W, a, WhTb, f1, f2);
    k2_attn<<<N / 16, 256, 0, stream>>>(adj, WhTb, f1, f2, out);
}

// Round 8
// 473.797 us; speedup vs baseline: 1.0226x; 1.0226x over previous
//
#include <hip/hip_runtime.h>
#include <hip/hip_bf16.h>

#define N    8192
#define INF  256
#define OUTF 128
#define ALPHA 0.2f
#define JS   8          // j-split across blockIdx.y

typedef __attribute__((ext_vector_type(8))) short bf16x8;
typedef __attribute__((ext_vector_type(4))) float f32x4;

__device__ __forceinline__ unsigned short f2bf(float x) {
    union { float f; unsigned u; } v; v.f = x;
    unsigned r = v.u + 0x7fff + ((v.u >> 16) & 1);   // RNE
    return (unsigned short)(r >> 16);
}

// ---------------- Kernel 1: WhT_b = blocked bf16 (h@W)^T ; f1 ; f2 ----------
// 8 rows/block, 256 threads, grid 1024. hs row-major in LDS (coalesced stage,
// broadcast reads). W direct from L2, unroll-8. WhT_b layout:
// [jblk=j/32][c][j%32] ushort (8 KB/tile) -> k2 B-loads are lane-contiguous.
__global__ __launch_bounds__(256) void k1_wh(
        const float* __restrict__ h, const float* __restrict__ W,
        const float* __restrict__ a,
        unsigned short* __restrict__ WhTb, float* __restrict__ f1, float* __restrict__ f2) {
    __shared__ float hs[8][INF];          // 8 KB
    const int t  = threadIdx.x;
    const int i0 = blockIdx.x * 8;

    #pragma unroll
    for (int u = 0; u < 2; ++u) {
        int idx = u * 256 + t;
        int r   = idx >> 6;               // 0..7 (wave-uniform)
        int kq  = idx & 63;               // lane-consecutive -> coalesced
        *(float4*)&hs[r][kq * 4] = *(const float4*)(h + (size_t)(i0 + r) * INF + kq * 4);
    }
    __syncthreads();

    const int rg = t >> 5;                // 0..7 : row
    const int ct = t & 31;                // 0..31 : col group
    float acc[4] = {0.f, 0.f, 0.f, 0.f};

    #pragma unroll 8
    for (int k = 0; k < INF; ++k) {
        float4 wv = *(const float4*)(W + (size_t)k * OUTF + ct * 4);
        float  hx = hs[rg][k];
        acc[0] += hx * wv.x; acc[1] += hx * wv.y;
        acc[2] += hx * wv.z; acc[3] += hx * wv.w;
    }

    const int r0 = i0 + rg;               // j index
    const int jb = r0 >> 5;
    const int jo = r0 & 31;
    #pragma unroll
    for (int cc = 0; cc < 4; ++cc)
        WhTb[(size_t)jb * 4096 + (ct * 4 + cc) * 32 + jo] = f2bf(acc[cc]);

    const float4 a1v = *(const float4*)(a + ct * 4);
    const float4 a2v = *(const float4*)(a + OUTF + ct * 4);
    float p1 = acc[0]*a1v.x + acc[1]*a1v.y + acc[2]*a1v.z + acc[3]*a1v.w;
    float p2 = acc[0]*a2v.x + acc[1]*a2v.y + acc[2]*a2v.z + acc[3]*a2v.w;
    #pragma unroll
    for (int off = 16; off > 0; off >>= 1) {
        p1 += __shfl_down(p1, off, 32);
        p2 += __shfl_down(p2, off, 32);
    }
    if (ct == 0) { f1[r0] = p1; f2[r0] = p2; }
}

// ---------------- Kernel 2: MFMA attention partials, zero LDS, high TLP -------
// One-pass masked softmax (exact vs ref; verified rounds 1-7). Grid (N/64, JS)
// = 1024 blocks -> 4 blocks/CU = 16 waves/CU (TLP hides L2/HBM latency; no
// reliance on compiler-honored prefetch distance). Block = 4 waves; wave wv
// owns rows i0+wv*16..+15 over the 1024-wide j-span of blockIdx.y, NT=32.
// adj: named depth-2 prefetch (spill-free per rounds 6/7). B-frags: coalesced
// 16B loads from blocked WhT (L2-hot), scheduled by the compiler, covered by
// TLP. Partials to global; k3 combines.
struct PFA { int4 a0, a1; };

__device__ __forceinline__ PFA ldadj(const int* __restrict__ ap, int jt) {
    PFA p;
    p.a0 = *(const int4*)(ap + (size_t)jt * 32);
    p.a1 = *(const int4*)(ap + (size_t)jt * 32 + 4);
    return p;
}

__device__ __forceinline__ float pleak(float f1r, float fv, int av, float& dsum) {
    float s = f1r + fv;
    float e = fmaxf(s, ALPHA * s);        // leaky-relu, branch-free
    float p = (av > 0) ? __expf(e) : 0.f;
    dsum += p;                            // fp32 den (<=1e-5 rel delta vs ref)
    return p;
}

#define K2STEP(PFV, JT)                                                     \
    {                                                                       \
        const unsigned short* wp_ = WhTb + ((size_t)(tile0 + (JT))) * 4096 + laneb; \
        bf16x8 b0_ = *(const bf16x8*)(wp_);                                 \
        bf16x8 b1_ = *(const bf16x8*)(wp_ + 512);                           \
        bf16x8 b2_ = *(const bf16x8*)(wp_ + 1024);                          \
        bf16x8 b3_ = *(const bf16x8*)(wp_ + 1536);                          \
        bf16x8 b4_ = *(const bf16x8*)(wp_ + 2048);                          \
        bf16x8 b5_ = *(const bf16x8*)(wp_ + 2560);                          \
        bf16x8 b6_ = *(const bf16x8*)(wp_ + 3072);                          \
        bf16x8 b7_ = *(const bf16x8*)(wp_ + 3584);                          \
        float4 F0_ = *(const float4*)(f2p + (size_t)(JT) * 32);             \
        float4 F1_ = *(const float4*)(f2p + (size_t)(JT) * 32 + 4);         \
        int4 A0_ = PFV.a0, A1_ = PFV.a1;                                    \
        if ((JT) + 2 < NT) PFV = ldadj(adjp, (JT) + 2);                     \
        float p0_ = pleak(f1r, F0_.x, A0_.x, dsum);                         \
        float p1_ = pleak(f1r, F0_.y, A0_.y, dsum);                         \
        float p2_ = pleak(f1r, F0_.z, A0_.z, dsum);                         \
        float p3_ = pleak(f1r, F0_.w, A0_.w, dsum);                         \
        float p4_ = pleak(f1r, F1_.x, A1_.x, dsum);                         \
        float p5_ = pleak(f1r, F1_.y, A1_.y, dsum);                         \
        float p6_ = pleak(f1r, F1_.z, A1_.z, dsum);                         \
        float p7_ = pleak(f1r, F1_.w, A1_.w, dsum);                         \
        union { __hip_bfloat162 hh[4]; bf16x8 v; } pk_;                     \
        pk_.hh[0] = __float22bfloat162_rn(make_float2(p0_, p1_));           \
        pk_.hh[1] = __float22bfloat162_rn(make_float2(p2_, p3_));           \
        pk_.hh[2] = __float22bfloat162_rn(make_float2(p4_, p5_));           \
        pk_.hh[3] = __float22bfloat162_rn(make_float2(p6_, p7_));           \
        bf16x8 afrag = pk_.v;                                               \
        acc0 = __builtin_amdgcn_mfma_f32_16x16x32_bf16(afrag, b0_, acc0, 0, 0, 0); \
        acc1 = __builtin_amdgcn_mfma_f32_16x16x32_bf16(afrag, b1_, acc1, 0, 0, 0); \
        acc2 = __builtin_amdgcn_mfma_f32_16x16x32_bf16(afrag, b2_, acc2, 0, 0, 0); \
        acc3 = __builtin_amdgcn_mfma_f32_16x16x32_bf16(afrag, b3_, acc3, 0, 0, 0); \
        acc4 = __builtin_amdgcn_mfma_f32_16x16x32_bf16(afrag, b4_, acc4, 0, 0, 0); \
        acc5 = __builtin_amdgcn_mfma_f32_16x16x32_bf16(afrag, b5_, acc5, 0, 0, 0); \
        acc6 = __builtin_amdgcn_mfma_f32_16x16x32_bf16(afrag, b6_, acc6, 0, 0, 0); \
        acc7 = __builtin_amdgcn_mfma_f32_16x16x32_bf16(afrag, b7_, acc7, 0, 0, 0); \
    }

__global__ __launch_bounds__(256, 4) void k2_attn(
        const int* __restrict__ adj, const unsigned short* __restrict__ WhTb,
        const float* __restrict__ f1, const float* __restrict__ f2,
        float* __restrict__ num, float* __restrict__ den) {
    const int t    = threadIdx.x;
    const int wv   = t >> 6;              // 0..3 : wave -> row-tile
    const int ln   = t & 63;
    const int m16  = ln & 15;             // A row within 16-tile
    const int quad = ln >> 4;             // 0..3
    const int i0   = blockIdx.x * 64;
    const int s    = blockIdx.y;          // j-split index
    const int row  = i0 + wv * 16 + m16;

    const float f1r  = f1[row];
    const int   j0   = s * (N / JS);      // 1024-wide span
    const int   NT   = (N / JS) / 32;     // 32 K-steps
    const int   tile0 = s * NT;           // first 32-j tile index

    const int*   adjp  = adj + (size_t)row * N + j0 + quad * 8;
    const float* f2p   = f2 + j0 + quad * 8;
    const int    laneb = m16 * 32 + quad * 8;   // ushort offset in 8 KB j-tile

    f32x4 acc0 = {0.f,0.f,0.f,0.f}, acc1 = {0.f,0.f,0.f,0.f};
    f32x4 acc2 = {0.f,0.f,0.f,0.f}, acc3 = {0.f,0.f,0.f,0.f};
    f32x4 acc4 = {0.f,0.f,0.f,0.f}, acc5 = {0.f,0.f,0.f,0.f};
    f32x4 acc6 = {0.f,0.f,0.f,0.f}, acc7 = {0.f,0.f,0.f,0.f};
    float dsum = 0.f;

    PFA pf0 = ldadj(adjp, 0);             // named depth-2 (spill-free)
    PFA pf1 = ldadj(adjp, 1);

    for (int jt = 0; jt < NT; jt += 2) {
        K2STEP(pf0, jt)
        K2STEP(pf1, jt + 1)
    }

    // den partial: sum the 4 quads of each row
    dsum += __shfl_xor(dsum, 16);
    dsum += __shfl_xor(dsum, 32);
    if (quad == 0) den[(size_t)s * N + row] = dsum;

    // num partial: D layout col=lane&15, row=quad*4+reg (64B-contiguous per quad)
    float* np = num + (size_t)s * N * OUTF;
    #pragma unroll
    for (int r = 0; r < 4; ++r) {
        const size_t orow = (size_t)(i0 + wv * 16 + quad * 4 + r) * OUTF;
        np[orow + 0 * 16 + m16] = acc0[r];
        np[orow + 1 * 16 + m16] = acc1[r];
        np[orow + 2 * 16 + m16] = acc2[r];
        np[orow + 3 * 16 + m16] = acc3[r];
        np[orow + 4 * 16 + m16] = acc4[r];
        np[orow + 5 * 16 + m16] = acc5[r];
        np[orow + 6 * 16 + m16] = acc6[r];
        np[orow + 7 * 16 + m16] = acc7[r];
    }
}

// ---------------- Kernel 3: combine JS partials, normalize ----------------
__global__ __launch_bounds__(256) void k3_combine(
        const float* __restrict__ num, const float* __restrict__ den,
        float* __restrict__ out) {
    const int idx = blockIdx.x * 256 + threadIdx.x;   // float4 index
    const int row = idx >> 5;
    const int c4  = (idx & 31) * 4;
    float4 ns = {0.f,0.f,0.f,0.f};
    float  ds = 0.f;
    #pragma unroll
    for (int s = 0; s < JS; ++s) {
        float4 nv = *(const float4*)(num + ((size_t)s * N + row) * OUTF + c4);
        ns.x += nv.x; ns.y += nv.y; ns.z += nv.z; ns.w += nv.w;
        ds += den[(size_t)s * N + row];
    }
    const float inv = 1.0f / ds;
    float4 o = {ns.x * inv, ns.y * inv, ns.z * inv, ns.w * inv};
    *(float4*)(out + (size_t)row * OUTF + c4) = o;
}

extern "C" void kernel_launch(void* const* d_in, const int* in_sizes, int n_in,
                              void* d_out, int out_size, void* d_ws, size_t ws_size,
                              hipStream_t stream) {
    const float* h   = (const float*)d_in[0];   // (8192, 256)
    const int*   adj = (const int*)  d_in[1];   // (8192, 8192)
    const float* W   = (const float*)d_in[2];   // (256, 128)
    const float* a   = (const float*)d_in[3];   // (256, 1)
    float* out = (float*)d_out;                 // (8192, 128)

    unsigned short* WhTb = (unsigned short*)d_ws;   // 2 MB blocked bf16
    float* f1  = (float*)(WhTb + (size_t)N * OUTF);
    float* f2  = f1 + N;
    float* den = f2 + N;                            // JS * N
    float* num = den + (size_t)JS * N;              // JS * N * OUTF (32 MB)

    k1_wh     <<<N / 8, 256, 0, stream>>>(h, W, a, WhTb, f1, f2);
    k2_attn   <<<dim3(N / 64, JS), 256, 0, stream>>>(adj, WhTb, f1, f2, num, den);
    k3_combine<<<(N * OUTF / 4) / 256, 256, 0, stream>>>(num, den, out);
}

// Round 9
// 452.786 us; speedup vs baseline: 1.0700x; 1.0464x over previous
//
#include <hip/hip_runtime.h>
#include <hip/hip_bf16.h>

#define N    8192
#define INF  256
#define OUTF 128
#define ALPHA 0.2f
#define JS   16              // j-split across blockIdx.y
#define NTS  (N / JS / 32)   // 16 K-steps per block

typedef __attribute__((ext_vector_type(8))) short bf16x8;
typedef __attribute__((ext_vector_type(4))) float f32x4;

__device__ __forceinline__ unsigned short f2bf(float x) {
    union { float f; unsigned u; } v; v.f = x;
    unsigned r = v.u + 0x7fff + ((v.u >> 16) & 1);   // RNE
    return (unsigned short)(r >> 16);
}

// ---------------- Kernel 0: bit-pack adj (268 MB -> 8 MB) --------------------
// Thread g packs word g: bits[r][j/32] bit (j%32) = adj[r][j] > 0.
// Reads 128 B/thread (L1 merges the 8 int4s); writes consecutive uints.
__global__ __launch_bounds__(256) void k0_pack(
        const int* __restrict__ adj, unsigned* __restrict__ bits) {
    const size_t g = (size_t)blockIdx.x * 256 + threadIdx.x;   // word idx, 2M
    const int4* p = (const int4*)adj + g * 8;                  // 32 ints
    unsigned b = 0;
    #pragma unroll
    for (int u = 0; u < 8; ++u) {
        int4 v = p[u];
        b |= (v.x > 0 ? 1u : 0u) << (u * 4 + 0);
        b |= (v.y > 0 ? 1u : 0u) << (u * 4 + 1);
        b |= (v.z > 0 ? 1u : 0u) << (u * 4 + 2);
        b |= (v.w > 0 ? 1u : 0u) << (u * 4 + 3);
    }
    bits[g] = b;
}

// ---------------- Kernel 1: WhT_b = blocked bf16 (h@W)^T ; f1 ; f2 ----------
// 8 rows/block, 256 threads, grid 1024. WhT_b: [jblk=j/32][c][j%32] ushort
// (8 KB per 32-j tile) -> k2 B-loads/stages are lane-contiguous.
__global__ __launch_bounds__(256) void k1_wh(
        const float* __restrict__ h, const float* __restrict__ W,
        const float* __restrict__ a,
        unsigned short* __restrict__ WhTb, float* __restrict__ f1, float* __restrict__ f2) {
    __shared__ float hs[8][INF];          // 8 KB
    const int t  = threadIdx.x;
    const int i0 = blockIdx.x * 8;

    #pragma unroll
    for (int u = 0; u < 2; ++u) {
        int idx = u * 256 + t;
        int r   = idx >> 6;               // 0..7 (wave-uniform)
        int kq  = idx & 63;
        *(float4*)&hs[r][kq * 4] = *(const float4*)(h + (size_t)(i0 + r) * INF + kq * 4);
    }
    __syncthreads();

    const int rg = t >> 5;                // 0..7 : row
    const int ct = t & 31;                // 0..31 : col group
    float acc[4] = {0.f, 0.f, 0.f, 0.f};

    #pragma unroll 8
    for (int k = 0; k < INF; ++k) {
        float4 wv = *(const float4*)(W + (size_t)k * OUTF + ct * 4);
        float  hx = hs[rg][k];
        acc[0] += hx * wv.x; acc[1] += hx * wv.y;
        acc[2] += hx * wv.z; acc[3] += hx * wv.w;
    }

    const int r0 = i0 + rg;               // j index
    const int jb = r0 >> 5;
    const int jo = r0 & 31;
    #pragma unroll
    for (int cc = 0; cc < 4; ++cc)
        WhTb[(size_t)jb * 4096 + (ct * 4 + cc) * 32 + jo] = f2bf(acc[cc]);

    const float4 a1v = *(const float4*)(a + ct * 4);
    const float4 a2v = *(const float4*)(a + OUTF + ct * 4);
    float p1 = acc[0]*a1v.x + acc[1]*a1v.y + acc[2]*a1v.z + acc[3]*a1v.w;
    float p2 = acc[0]*a2v.x + acc[1]*a2v.y + acc[2]*a2v.z + acc[3]*a2v.w;
    #pragma unroll
    for (int off = 16; off > 0; off >>= 1) {
        p1 += __shfl_down(p1, off, 32);
        p2 += __shfl_down(p2, off, 32);
    }
    if (ct == 0) { f1[r0] = p1; f2[r0] = p2; }
}

// ---------------- Kernel 2: MFMA attention, bitmask adj + LDS-staged B -------
// One-pass masked softmax (exact vs ref; verified rounds 1-8; bit set <=> adj>0).
// Grid (N/64, JS): 64 rows/block, 4 waves, span 512 j, NTS=16 K-steps.
// Per step: bits come from a pre-loaded uint4 (4 steps/load, quad-broadcast,
// L2-hot 8 MB), f2 from LDS (staged once), B-frags from LDS (8 KB tile staged
// once per block per step, double-buffered, 1 barrier/step). Per-wave-step
// L2 line-requests ~36 (vs ~200 in r8) -> off the request-rate ceiling.
__device__ __forceinline__ float pbit(float f1r, float fv, unsigned byte_,
                                      int u, float& dsum) {
    float s = f1r + fv;
    float e = fmaxf(s, ALPHA * s);        // leaky-relu, branch-free
    float p = (byte_ & (1u << u)) ? __expf(e) : 0.f;
    dsum += p;
    return p;
}

#define K2SUB(WORD, JT)                                                      \
    {                                                                        \
        const int cb_ = (JT) & 1, nb_ = ((JT) + 1) & 1;                      \
        float4 sg0_, sg1_;                                                   \
        if ((JT) + 1 < NTS) {                                                \
            const char* ws_ = (const char*)WhTb + (size_t)(tile0 + (JT) + 1) * 8192; \
            sg0_ = *(const float4*)(ws_ + t * 16);                           \
            sg1_ = *(const float4*)(ws_ + 4096 + t * 16);                    \
        }                                                                    \
        float4 F0_ = *(const float4*)&f2s[(JT) * 32 + quad * 8];             \
        float4 F1_ = *(const float4*)&f2s[(JT) * 32 + quad * 8 + 4];         \
        unsigned byte_ = ((WORD) >> (quad << 3)) & 0xffu;                    \
        float p0_ = pbit(f1r, F0_.x, byte_, 0, dsum);                        \
        float p1_ = pbit(f1r, F0_.y, byte_, 1, dsum);                        \
        float p2_ = pbit(f1r, F0_.z, byte_, 2, dsum);                        \
        float p3_ = pbit(f1r, F0_.w, byte_, 3, dsum);                        \
        float p4_ = pbit(f1r, F1_.x, byte_, 4, dsum);                        \
        float p5_ = pbit(f1r, F1_.y, byte_, 5, dsum);                        \
        float p6_ = pbit(f1r, F1_.z, byte_, 6, dsum);                        \
        float p7_ = pbit(f1r, F1_.w, byte_, 7, dsum);                        \
        union { __hip_bfloat162 hh[4]; bf16x8 v; } pk_;                      \
        pk_.hh[0] = __float22bfloat162_rn(make_float2(p0_, p1_));            \
        pk_.hh[1] = __float22bfloat162_rn(make_float2(p2_, p3_));            \
        pk_.hh[2] = __float22bfloat162_rn(make_float2(p4_, p5_));            \
        pk_.hh[3] = __float22bfloat162_rn(make_float2(p6_, p7_));            \
        bf16x8 afrag = pk_.v;                                                \
        const char* bb_ = (const char*)&bsm[cb_][0] + laneb2;                \
        bf16x8 b0_ = *(const bf16x8*)(bb_);                                  \
        bf16x8 b1_ = *(const bf16x8*)(bb_ + 1024);                           \
        bf16x8 b2_ = *(const bf16x8*)(bb_ + 2048);                           \
        bf16x8 b3_ = *(const bf16x8*)(bb_ + 3072);                           \
        bf16x8 b4_ = *(const bf16x8*)(bb_ + 4096);                           \
        bf16x8 b5_ = *(const bf16x8*)(bb_ + 5120);                           \
        bf16x8 b6_ = *(const bf16x8*)(bb_ + 6144);                           \
        bf16x8 b7_ = *(const bf16x8*)(bb_ + 7168);                           \
        acc0 = __builtin_amdgcn_mfma_f32_16x16x32_bf16(afrag, b0_, acc0, 0, 0, 0); \
        acc1 = __builtin_amdgcn_mfma_f32_16x16x32_bf16(afrag, b1_, acc1, 0, 0, 0); \
        acc2 = __builtin_amdgcn_mfma_f32_16x16x32_bf16(afrag, b2_, acc2, 0, 0, 0); \
        acc3 = __builtin_amdgcn_mfma_f32_16x16x32_bf16(afrag, b3_, acc3, 0, 0, 0); \
        acc4 = __builtin_amdgcn_mfma_f32_16x16x32_bf16(afrag, b4_, acc4, 0, 0, 0); \
        acc5 = __builtin_amdgcn_mfma_f32_16x16x32_bf16(afrag, b5_, acc5, 0, 0, 0); \
        acc6 = __builtin_amdgcn_mfma_f32_16x16x32_bf16(afrag, b6_, acc6, 0, 0, 0); \
        acc7 = __builtin_amdgcn_mfma_f32_16x16x32_bf16(afrag, b7_, acc7, 0, 0, 0); \
        if ((JT) + 1 < NTS) {                                                \
            char* bd_ = (char*)&bsm[nb_][0];                                 \
            *(float4*)(bd_ + t * 16)        = sg0_;                          \
            *(float4*)(bd_ + 4096 + t * 16) = sg1_;                          \
        }                                                                    \
        __syncthreads();                                                     \
    }

__global__ __launch_bounds__(256, 5) void k2_attn(
        const unsigned* __restrict__ bits, const unsigned short* __restrict__ WhTb,
        const float* __restrict__ f1, const float* __restrict__ f2,
        float* __restrict__ num, float* __restrict__ den) {
    __shared__ unsigned short bsm[2][4096];   // 2 x 8 KB B-tile double buffer
    __shared__ float f2s[512];                // block's f2 span (2 KB)

    const int t    = threadIdx.x;
    const int wv   = t >> 6;              // 0..3 : wave -> row-tile
    const int ln   = t & 63;
    const int m16  = ln & 15;
    const int quad = ln >> 4;
    const int i0   = blockIdx.x * 64;
    const int s    = blockIdx.y;
    const int row  = i0 + wv * 16 + m16;
    const int tile0 = s * NTS;
    const int j0    = s * (N / JS);
    const int laneb2 = (m16 * 32 + quad * 8) * 2;   // byte offset in 8 KB tile

    // stage f2 span + B tile 0
    if (t < 128) *(float4*)&f2s[t * 4] = *(const float4*)(f2 + j0 + t * 4);
    {
        const char* ws0 = (const char*)WhTb + (size_t)tile0 * 8192;
        float4 s0 = *(const float4*)(ws0 + t * 16);
        float4 s1 = *(const float4*)(ws0 + 4096 + t * 16);
        char* bd = (char*)&bsm[0][0];
        *(float4*)(bd + t * 16)        = s0;
        *(float4*)(bd + 4096 + t * 16) = s1;
    }

    const float f1r = f1[row];
    // bit words: word idx = row*256 + tileG; uint4 = 4 K-steps (quad-broadcast)
    const uint4* brow = (const uint4*)((const char*)bits + (size_t)row * 1024 + (size_t)tile0 * 4);
    uint4 bw0 = brow[0], bw1 = brow[1], bw2 = brow[2], bw3 = brow[3];

    f32x4 acc0 = {0.f,0.f,0.f,0.f}, acc1 = {0.f,0.f,0.f,0.f};
    f32x4 acc2 = {0.f,0.f,0.f,0.f}, acc3 = {0.f,0.f,0.f,0.f};
    f32x4 acc4 = {0.f,0.f,0.f,0.f}, acc5 = {0.f,0.f,0.f,0.f};
    f32x4 acc6 = {0.f,0.f,0.f,0.f}, acc7 = {0.f,0.f,0.f,0.f};
    float dsum = 0.f;

    __syncthreads();                      // f2s + bsm[0] ready

    K2SUB(bw0.x,  0) K2SUB(bw0.y,  1) K2SUB(bw0.z,  2) K2SUB(bw0.w,  3)
    K2SUB(bw1.x,  4) K2SUB(bw1.y,  5) K2SUB(bw1.z,  6) K2SUB(bw1.w,  7)
    K2SUB(bw2.x,  8) K2SUB(bw2.y,  9) K2SUB(bw2.z, 10) K2SUB(bw2.w, 11)
    K2SUB(bw3.x, 12) K2SUB(bw3.y, 13) K2SUB(bw3.z, 14) K2SUB(bw3.w, 15)

    // den partial: sum the 4 quads of each row
    dsum += __shfl_xor(dsum, 16);
    dsum += __shfl_xor(dsum, 32);
    if (quad == 0) den[(size_t)s * N + row] = dsum;

    // num partial: D layout col=lane&15, row=quad*4+reg
    float* np = num + (size_t)s * N * OUTF;
    #pragma unroll
    for (int r = 0; r < 4; ++r) {
        const size_t orow = (size_t)(i0 + wv * 16 + quad * 4 + r) * OUTF;
        np[orow + 0 * 16 + m16] = acc0[r];
        np[orow + 1 * 16 + m16] = acc1[r];
        np[orow + 2 * 16 + m16] = acc2[r];
        np[orow + 3 * 16 + m16] = acc3[r];
        np[orow + 4 * 16 + m16] = acc4[r];
        np[orow + 5 * 16 + m16] = acc5[r];
        np[orow + 6 * 16 + m16] = acc6[r];
        np[orow + 7 * 16 + m16] = acc7[r];
    }
}

// ---------------- Kernel 3: combine JS partials, normalize ----------------
__global__ __launch_bounds__(256) void k3_combine(
        const float* __restrict__ num, const float* __restrict__ den,
        float* __restrict__ out) {
    const int idx = blockIdx.x * 256 + threadIdx.x;   // float4 index
    const int row = idx >> 5;
    const int c4  = (idx & 31) * 4;
    float4 ns = {0.f,0.f,0.f,0.f};
    float  ds = 0.f;
    #pragma unroll
    for (int s = 0; s < JS; ++s) {
        float4 nv = *(const float4*)(num + ((size_t)s * N + row) * OUTF + c4);
        ns.x += nv.x; ns.y += nv.y; ns.z += nv.z; ns.w += nv.w;
        ds += den[(size_t)s * N + row];
    }
    const float inv = 1.0f / ds;
    float4 o = {ns.x * inv, ns.y * inv, ns.z * inv, ns.w * inv};
    *(float4*)(out + (size_t)row * OUTF + c4) = o;
}

extern "C" void kernel_launch(void* const* d_in, const int* in_sizes, int n_in,
                              void* d_out, int out_size, void* d_ws, size_t ws_size,
                              hipStream_t stream) {
    const float* h   = (const float*)d_in[0];   // (8192, 256)
    const int*   adj = (const int*)  d_in[1];   // (8192, 8192)
    const float* W   = (const float*)d_in[2];   // (256, 128)
    const float* a   = (const float*)d_in[3];   // (256, 1)
    float* out = (float*)d_out;                 // (8192, 128)

    unsigned short* WhTb = (unsigned short*)d_ws;          // 2 MB blocked bf16
    float*    f1   = (float*)(WhTb + (size_t)N * OUTF);    // 32 KB
    float*    f2   = f1 + N;                               // 32 KB
    float*    den  = f2 + N;                               // JS*N = 512 KB
    unsigned* bits = (unsigned*)(den + (size_t)JS * N);    // 8 MB
    float*    num  = (float*)(bits + (size_t)N * (N / 32));// JS*N*OUTF = 64 MB

    k1_wh     <<<N / 8, 256, 0, stream>>>(h, W, a, WhTb, f1, f2);
    k0_pack   <<<(N / 32) * (N / 256), 256, 0, stream>>>(adj, bits);
    k2_attn   <<<dim3(N / 64, JS), 256, 0, stream>>>(bits, WhTb, f1, f2, num, den);
    k3_combine<<<(N * OUTF / 4) / 256, 256, 0, stream>>>(num, den, out);
}

// Round 10
// 431.356 us; speedup vs baseline: 1.1232x; 1.0497x over previous
//
#include <hip/hip_runtime.h>
#include <hip/hip_bf16.h>

#define N    8192
#define INF  256
#define OUTF 128
#define ALPHA 0.2f
#define JS   8               // j-split across blockIdx.y
#define NTS  (N / JS / 32)   // 32 K-steps per block

typedef __attribute__((ext_vector_type(8))) short bf16x8;
typedef __attribute__((ext_vector_type(4))) float f32x4;

__device__ __forceinline__ unsigned short f2bf(float x) {
    union { float f; unsigned u; } v; v.f = x;
    unsigned r = v.u + 0x7fff + ((v.u >> 16) & 1);   // RNE
    return (unsigned short)(r >> 16);
}

// async global->LDS, 16 B per lane (wave-uniform LDS base + lane*16)
__device__ __forceinline__ void gll16(const void* g, void* l) {
    __builtin_amdgcn_global_load_lds(
        (const __attribute__((address_space(1))) unsigned*)g,
        (__attribute__((address_space(3))) unsigned*)l, 16, 0, 0);
}

// ---------------- Kernel 0+1 fused ------------------------------------------
// Blocks [0,1024): k1 body — WhT_b = blocked bf16 (h@W)^T ; f1 ; f2.
// Blocks [1024,9216): k0 body — bit-pack adj (268 MB -> 8 MB), coalesced.
// k1 runs concurrently under k0's HBM stream (they're independent).
__global__ __launch_bounds__(256) void k01_prep(
        const int* __restrict__ adj, unsigned* __restrict__ bits,
        const float* __restrict__ h, const float* __restrict__ W,
        const float* __restrict__ a,
        unsigned short* __restrict__ WhTb, float* __restrict__ f1, float* __restrict__ f2) {
    __shared__ float hs[8][INF];          // 8 KB (k1 blocks only)
    const int t = threadIdx.x;

    if (blockIdx.x >= 1024) {
        // ---- k0: pack 32 adj ints -> 1 bit word per thread ----
        const size_t g = (size_t)(blockIdx.x - 1024) * 256 + t;   // word idx, 2M
        const int4* p = (const int4*)adj + g * 8;
        unsigned b = 0;
        #pragma unroll
        for (int u = 0; u < 8; ++u) {
            int4 v = p[u];
            b |= (v.x > 0 ? 1u : 0u) << (u * 4 + 0);
            b |= (v.y > 0 ? 1u : 0u) << (u * 4 + 1);
            b |= (v.z > 0 ? 1u : 0u) << (u * 4 + 2);
            b |= (v.w > 0 ? 1u : 0u) << (u * 4 + 3);
        }
        bits[g] = b;
        return;
    }

    // ---- k1: 8 rows/block ----
    const int i0 = blockIdx.x * 8;
    #pragma unroll
    for (int u = 0; u < 2; ++u) {
        int idx = u * 256 + t;
        int r   = idx >> 6;               // 0..7 (wave-uniform)
        int kq  = idx & 63;
        *(float4*)&hs[r][kq * 4] = *(const float4*)(h + (size_t)(i0 + r) * INF + kq * 4);
    }
    __syncthreads();

    const int rg = t >> 5;                // 0..7 : row
    const int ct = t & 31;                // 0..31 : col group
    float acc[4] = {0.f, 0.f, 0.f, 0.f};

    #pragma unroll 8
    for (int k = 0; k < INF; ++k) {
        float4 wv = *(const float4*)(W + (size_t)k * OUTF + ct * 4);
        float  hx = hs[rg][k];
        acc[0] += hx * wv.x; acc[1] += hx * wv.y;
        acc[2] += hx * wv.z; acc[3] += hx * wv.w;
    }

    const int r0 = i0 + rg;               // j index
    const int jb = r0 >> 5;
    const int jo = r0 & 31;
    #pragma unroll
    for (int cc = 0; cc < 4; ++cc)
        WhTb[(size_t)jb * 4096 + (ct * 4 + cc) * 32 + jo] = f2bf(acc[cc]);

    const float4 a1v = *(const float4*)(a + ct * 4);
    const float4 a2v = *(const float4*)(a + OUTF + ct * 4);
    float p1 = acc[0]*a1v.x + acc[1]*a1v.y + acc[2]*a1v.z + acc[3]*a1v.w;
    float p2 = acc[0]*a2v.x + acc[1]*a2v.y + acc[2]*a2v.z + acc[3]*a2v.w;
    #pragma unroll
    for (int off = 16; off > 0; off >>= 1) {
        p1 += __shfl_down(p1, off, 32);
        p2 += __shfl_down(p2, off, 32);
    }
    if (ct == 0) { f1[r0] = p1; f2[r0] = p2; }
}

// ---------------- Kernel 2: MFMA attention, bitmask adj + async LDS B -------
// One-pass masked softmax (exact vs ref; verified rounds 1-9). Grid (N/64,JS):
// 64 rows/block, 4 waves, 1024-j span, NTS=32 steps. Bits: L2-hot uint4 per
// 4 steps (double-buffered). B-tile: 8 KB staged per step via
// global_load_lds x2 (async, no VGPR round-trip), LDS double buffer, one
// barrier/step. f2 span (4 KB) staged once.
__device__ __forceinline__ float pbit(float f1r, float fv, unsigned byte_,
                                      int u, float& dsum) {
    float s = f1r + fv;
    float e = fmaxf(s, ALPHA * s);        // leaky-relu, branch-free
    float p = (byte_ & (1u << u)) ? __expf(e) : 0.f;
    dsum += p;
    return p;
}

// PH = compile-time buffer phase (JT&1); JT = runtime K-step index
#define K2SUB(WORD, PH, JT)                                                  \
    {                                                                        \
        if ((JT) + 1 < NTS) {                                                \
            const char* ws_ = (const char*)WhTb + (size_t)(tile0 + (JT) + 1) * 8192; \
            char* bd_ = (char*)&bsm[(PH) ^ 1][0];                            \
            gll16(ws_ + t * 16,        bd_ + wv * 1024 + 0);                 \
            gll16(ws_ + 4096 + t * 16, bd_ + 4096 + wv * 1024 + 0);          \
        }                                                                    \
        float4 F0_ = *(const float4*)&f2s[(JT) * 32 + quad * 8];             \
        float4 F1_ = *(const float4*)&f2s[(JT) * 32 + quad * 8 + 4];         \
        unsigned byte_ = ((WORD) >> (quad << 3)) & 0xffu;                    \
        float p0_ = pbit(f1r, F0_.x, byte_, 0, dsum);                        \
        float p1_ = pbit(f1r, F0_.y, byte_, 1, dsum);                        \
        float p2_ = pbit(f1r, F0_.z, byte_, 2, dsum);                        \
        float p3_ = pbit(f1r, F0_.w, byte_, 3, dsum);                        \
        float p4_ = pbit(f1r, F1_.x, byte_, 4, dsum);                        \
        float p5_ = pbit(f1r, F1_.y, byte_, 5, dsum);                        \
        float p6_ = pbit(f1r, F1_.z, byte_, 6, dsum);                        \
        float p7_ = pbit(f1r, F1_.w, byte_, 7, dsum);                        \
        union { __hip_bfloat162 hh[4]; bf16x8 v; } pk_;                      \
        pk_.hh[0] = __float22bfloat162_rn(make_float2(p0_, p1_));            \
        pk_.hh[1] = __float22bfloat162_rn(make_float2(p2_, p3_));            \
        pk_.hh[2] = __float22bfloat162_rn(make_float2(p4_, p5_));            \
        pk_.hh[3] = __float22bfloat162_rn(make_float2(p6_, p7_));            \
        bf16x8 afrag = pk_.v;                                                \
        const char* bb_ = (const char*)&bsm[PH][0] + laneb2;                 \
        bf16x8 b0_ = *(const bf16x8*)(bb_);                                  \
        bf16x8 b1_ = *(const bf16x8*)(bb_ + 1024);                           \
        bf16x8 b2_ = *(const bf16x8*)(bb_ + 2048);                           \
        bf16x8 b3_ = *(const bf16x8*)(bb_ + 3072);                           \
        bf16x8 b4_ = *(const bf16x8*)(bb_ + 4096);                           \
        bf16x8 b5_ = *(const bf16x8*)(bb_ + 5120);                           \
        bf16x8 b6_ = *(const bf16x8*)(bb_ + 6144);                           \
        bf16x8 b7_ = *(const bf16x8*)(bb_ + 7168);                           \
        acc0 = __builtin_amdgcn_mfma_f32_16x16x32_bf16(afrag, b0_, acc0, 0, 0, 0); \
        acc1 = __builtin_amdgcn_mfma_f32_16x16x32_bf16(afrag, b1_, acc1, 0, 0, 0); \
        acc2 = __builtin_amdgcn_mfma_f32_16x16x32_bf16(afrag, b2_, acc2, 0, 0, 0); \
        acc3 = __builtin_amdgcn_mfma_f32_16x16x32_bf16(afrag, b3_, acc3, 0, 0, 0); \
        acc4 = __builtin_amdgcn_mfma_f32_16x16x32_bf16(afrag, b4_, acc4, 0, 0, 0); \
        acc5 = __builtin_amdgcn_mfma_f32_16x16x32_bf16(afrag, b5_, acc5, 0, 0, 0); \
        acc6 = __builtin_amdgcn_mfma_f32_16x16x32_bf16(afrag, b6_, acc6, 0, 0, 0); \
        acc7 = __builtin_amdgcn_mfma_f32_16x16x32_bf16(afrag, b7_, acc7, 0, 0, 0); \
        __syncthreads();                                                     \
    }

__global__ __launch_bounds__(256, 4) void k2_attn(
        const unsigned* __restrict__ bits, const unsigned short* __restrict__ WhTb,
        const float* __restrict__ f1, const float* __restrict__ f2,
        float* __restrict__ num, float* __restrict__ den) {
    __shared__ unsigned short bsm[2][4096];   // 2 x 8 KB B-tile double buffer
    __shared__ float f2s[1024];               // block's f2 span (4 KB)

    const int t    = threadIdx.x;
    const int wv   = t >> 6;              // 0..3 : wave -> row-tile
    const int ln   = t & 63;
    const int m16  = ln & 15;
    const int quad = ln >> 4;
    const int i0   = blockIdx.x * 64;
    const int s    = blockIdx.y;
    const int row  = i0 + wv * 16 + m16;
    const int tile0 = s * NTS;
    const int j0    = s * (N / JS);
    const int laneb2 = (m16 * 32 + quad * 8) * 2;   // byte offset in 8 KB tile

    // stage f2 span + B tile 0 (async)
    *(float4*)&f2s[t * 4] = *(const float4*)(f2 + j0 + t * 4);
    {
        const char* ws0 = (const char*)WhTb + (size_t)tile0 * 8192;
        char* bd = (char*)&bsm[0][0];
        gll16(ws0 + t * 16,        bd + wv * 1024);
        gll16(ws0 + 4096 + t * 16, bd + 4096 + wv * 1024);
    }

    const float f1r = f1[row];
    const uint4* brow = (const uint4*)(bits + (size_t)row * 256 + tile0);

    f32x4 acc0 = {0.f,0.f,0.f,0.f}, acc1 = {0.f,0.f,0.f,0.f};
    f32x4 acc2 = {0.f,0.f,0.f,0.f}, acc3 = {0.f,0.f,0.f,0.f};
    f32x4 acc4 = {0.f,0.f,0.f,0.f}, acc5 = {0.f,0.f,0.f,0.f};
    f32x4 acc6 = {0.f,0.f,0.f,0.f}, acc7 = {0.f,0.f,0.f,0.f};
    float dsum = 0.f;

    uint4 bwc = brow[0];                  // bits double buffer (L2-hot)
    __syncthreads();                      // f2s + bsm[0] ready (drains vmcnt)

    for (int g = 0; g < NTS / 4; ++g) {   // 8 groups x 4 steps
        uint4 bwn = brow[(g + 1 < NTS / 4) ? g + 1 : g];
        const int jtb = g * 4;
        K2SUB(bwc.x, 0, jtb + 0)
        K2SUB(bwc.y, 1, jtb + 1)
        K2SUB(bwc.z, 0, jtb + 2)
        K2SUB(bwc.w, 1, jtb + 3)
        bwc = bwn;
    }

    // den partial: sum the 4 quads of each row
    dsum += __shfl_xor(dsum, 16);
    dsum += __shfl_xor(dsum, 32);
    if (quad == 0) den[(size_t)s * N + row] = dsum;

    // num partial: D layout col=lane&15, row=quad*4+reg
    float* np = num + (size_t)s * N * OUTF;
    #pragma unroll
    for (int r = 0; r < 4; ++r) {
        const size_t orow = (size_t)(i0 + wv * 16 + quad * 4 + r) * OUTF;
        np[orow + 0 * 16 + m16] = acc0[r];
        np[orow + 1 * 16 + m16] = acc1[r];
        np[orow + 2 * 16 + m16] = acc2[r];
        np[orow + 3 * 16 + m16] = acc3[r];
        np[orow + 4 * 16 + m16] = acc4[r];
        np[orow + 5 * 16 + m16] = acc5[r];
        np[orow + 6 * 16 + m16] = acc6[r];
        np[orow + 7 * 16 + m16] = acc7[r];
    }
}

// ---------------- Kernel 3: combine JS partials, normalize ----------------
__global__ __launch_bounds__(256) void k3_combine(
        const float* __restrict__ num, const float* __restrict__ den,
        float* __restrict__ out) {
    const int idx = blockIdx.x * 256 + threadIdx.x;   // float4 index
    const int row = idx >> 5;
    const int c4  = (idx & 31) * 4;
    float4 ns = {0.f,0.f,0.f,0.f};
    float  ds = 0.f;
    #pragma unroll
    for (int s = 0; s < JS; ++s) {
        float4 nv = *(const float4*)(num + ((size_t)s * N + row) * OUTF + c4);
        ns.x += nv.x; ns.y += nv.y; ns.z += nv.z; ns.w += nv.w;
        ds += den[(size_t)s * N + row];
    }
    const float inv = 1.0f / ds;
    float4 o = {ns.x * inv, ns.y * inv, ns.z * inv, ns.w * inv};
    *(float4*)(out + (size_t)row * OUTF + c4) = o;
}

extern "C" void kernel_launch(void* const* d_in, const int* in_sizes, int n_in,
                              void* d_out, int out_size, void* d_ws, size_t ws_size,
                              hipStream_t stream) {
    const float* h   = (const float*)d_in[0];   // (8192, 256)
    const int*   adj = (const int*)  d_in[1];   // (8192, 8192)
    const float* W   = (const float*)d_in[2];   // (256, 128)
    const float* a   = (const float*)d_in[3];   // (256, 1)
    float* out = (float*)d_out;                 // (8192, 128)

    unsigned short* WhTb = (unsigned short*)d_ws;          // 2 MB blocked bf16
    float*    f1   = (float*)(WhTb + (size_t)N * OUTF);    // 32 KB
    float*    f2   = f1 + N;                               // 32 KB
    float*    den  = f2 + N;                               // JS*N = 256 KB
    unsigned* bits = (unsigned*)(den + (size_t)JS * N);    // 8 MB
    float*    num  = (float*)(bits + (size_t)N * (N / 32));// JS*N*OUTF = 32 MB

    k01_prep  <<<1024 + (N / 32) * (N / 256), 256, 0, stream>>>(adj, bits, h, W, a, WhTb, f1, f2);
    k2_attn   <<<dim3(N / 64, JS), 256, 0, stream>>>(bits, WhTb, f1, f2, num, den);
    k3_combine<<<(N * OUTF / 4) / 256, 256, 0, stream>>>(num, den, out);
}